// Round 7
// baseline (876.281 us; speedup 1.0000x reference)
//
#include <hip/hip_runtime.h>

// ---------------------------------------------------------------------------
// PoetryModel: embed -> x_gates GEMM -> LSTM(128 steps) -> classifier GEMM
//              -> log_softmax over V -> out (B, V, S) f32
// B=64 S=128 V=8000 E=256 H=512 G=4H=2048
// ---------------------------------------------------------------------------

using u16   = unsigned short;
using u32   = unsigned int;
using u16x4 = __attribute__((ext_vector_type(4))) u16;
using u16x8 = __attribute__((ext_vector_type(8))) u16;
using u32x4 = __attribute__((ext_vector_type(4))) u32;
using bf16x8 = __attribute__((ext_vector_type(8))) __bf16;
using f32x4 = __attribute__((ext_vector_type(4))) float;

#define NB   64        // batch
#define NS   128       // seq len
#define NV   8000      // vocab
#define NVP  8192      // vocab padded to tile
#define NE   256       // embed dim
#define NH   512       // hidden
#define NG   2048      // 4*H
#define NBS  8192      // B*S
#define OUT_BSTRIDE 1024000   // V*S
#define XG_SSTRIDE  131072    // G*B

__device__ inline u16 f2bf(float f) {
    unsigned x = __builtin_bit_cast(unsigned, f);
    unsigned r = (x + 0x7FFFu + ((x >> 16) & 1u)) >> 16;
    return (u16)r;
}

__device__ inline bf16x8 ld_frag(const u16* p) {
    u16x8 v = *(const u16x8*)p;
    return __builtin_bit_cast(bf16x8, v);
}

// LLC-coherent ops: bypass L1+L2, never create/consume dirty L2 lines.
__device__ inline void store_llc(u32* p, u32 v) {
    asm volatile("global_store_dword %0, %1, off sc0 sc1"
                 :: "v"(p), "v"(v) : "memory");
}
__device__ inline u32x4 reload_llc(const u32* p) {
    u32x4 v;
    asm volatile("global_load_dwordx4 %0, %1, off sc0 sc1\n\t"
                 "s_waitcnt vmcnt(0)"
                 : "=v"(v) : "v"(p) : "memory");
    return v;
}
// 4 contiguous 16B tagged chunks (64B), one base address, single wait
__device__ inline void load_llc64(const u32* p, u32x4& a, u32x4& b,
                                  u32x4& c, u32x4& d) {
    asm volatile("global_load_dwordx4 %0, %4, off sc0 sc1\n\t"
                 "global_load_dwordx4 %1, %4, off offset:16 sc0 sc1\n\t"
                 "global_load_dwordx4 %2, %4, off offset:32 sc0 sc1\n\t"
                 "global_load_dwordx4 %3, %4, off offset:48 sc0 sc1\n\t"
                 "s_waitcnt vmcnt(0)"
                 : "=&v"(a), "=&v"(b), "=&v"(c), "=&v"(d)
                 : "v"(p) : "memory");
}

// poll one tagged 16B chunk until tag==stp, then drop tags -> LDS (8B)
__device__ inline void commit_chunk(u32x4 v, const u32* src, u16* dst, u32 stp) {
    for (;;) {
        u32 bad = ((v[0] >> 16) ^ stp) | ((v[1] >> 16) ^ stp) |
                  ((v[2] >> 16) ^ stp) | ((v[3] >> 16) ^ stp);
        if (!bad) break;
        v = reload_llc(src);
    }
    u16x4 h = {(u16)v[0], (u16)v[1], (u16)v[2], (u16)v[3]};
    *(u16x4*)dst = h;
}

// 4x4 transpose across lane quad {p} x element {r} (verified round 3)
__device__ inline void quad_transpose(float v[4], int p) {
    float tb[4];
    #pragma unroll
    for (int q2 = 0; q2 < 4; ++q2) tb[q2] = __shfl_xor(v[q2 ^ 2], 2);
    #pragma unroll
    for (int q2 = 0; q2 < 4; ++q2) v[q2] = (((q2 ^ p) & 2) ? tb[q2] : v[q2]);
    #pragma unroll
    for (int q2 = 0; q2 < 4; ++q2) tb[q2] = __shfl_xor(v[q2 ^ 1], 1);
    #pragma unroll
    for (int q2 = 0; q2 < 4; ++q2) v[q2] = (((q2 ^ p) & 1) ? tb[q2] : v[q2]);
}

__device__ inline float lstm_cell(const float v[4], float& c) {
    float i_ = 1.f / (1.f + __expf(-v[0]));
    float f_ = 1.f / (1.f + __expf(-v[1]));
    float e2 = __expf(2.f * v[2]);
    float g_ = 1.f - 2.f / (e2 + 1.f);
    float o_ = 1.f / (1.f + __expf(-v[3]));
    c = f_ * c + i_ * g_;
    float e2c = __expf(2.f * c);
    return o_ * (1.f - 2.f / (e2c + 1.f));
}

// ---------------------------------------------------------------- converts
__global__ void cvt_bf16(const float* __restrict__ s, u16* __restrict__ d, int n8) {
    const float4* s4 = (const float4*)s;
    for (int i = blockIdx.x * blockDim.x + threadIdx.x; i < n8;
         i += gridDim.x * blockDim.x) {
        float4 a = s4[2 * i], b = s4[2 * i + 1];
        u16x8 o;
        o[0] = f2bf(a.x); o[1] = f2bf(a.y); o[2] = f2bf(a.z); o[3] = f2bf(a.w);
        o[4] = f2bf(b.x); o[5] = f2bf(b.y); o[6] = f2bf(b.z); o[7] = f2bf(b.w);
        ((u16x8*)d)[i] = o;
    }
}

// ------------------------------------------------- K1: x_gates = x @ W_ih^T
__global__ __launch_bounds__(256) void k1_xgates(
    const u16* __restrict__ Wih, const u16* __restrict__ emb,
    const int* __restrict__ toks,
    const float* __restrict__ bih, const float* __restrict__ bhh,
    float* __restrict__ xg)
{
    __shared__ u16x8 Al8[512];   // [128][32] bf16
    __shared__ u16x8 Bl8[512];
    u16* Al = (u16*)Al8;
    u16* Bl = (u16*)Bl8;

    const int t = threadIdx.x;
    const int lane = t & 63, w = t >> 6;
    const int wm = w >> 1, wn = w & 1;
    const int gtile = blockIdx.y * 128, mtile = blockIdx.x * 128;

    const int r0 = t >> 2, r1 = r0 + 64, q = t & 3;
    const int m0 = mtile + r0, m1 = mtile + r1;
    const int tok0 = toks[(m0 & 63) * NS + (m0 >> 6)];
    const int tok1 = toks[(m1 & 63) * NS + (m1 >> 6)];

    f32x4 acc[4][4];
    for (int i = 0; i < 4; ++i)
        for (int j = 0; j < 4; ++j) acc[i][j] = {0.f, 0.f, 0.f, 0.f};

    const int kc8 = (lane >> 4) * 8;
    for (int kk = 0; kk < 8; ++kk) {
        const int k0 = kk * 32;
        *(u16x8*)&Al[t * 8]         = *(const u16x8*)&Wih[(gtile + r0) * NE + k0 + q * 8];
        *(u16x8*)&Al[(t + 256) * 8] = *(const u16x8*)&Wih[(gtile + r1) * NE + k0 + q * 8];
        *(u16x8*)&Bl[t * 8]         = *(const u16x8*)&emb[tok0 * NE + k0 + q * 8];
        *(u16x8*)&Bl[(t + 256) * 8] = *(const u16x8*)&emb[tok1 * NE + k0 + q * 8];
        __syncthreads();
        bf16x8 af[4], bf[4];
        #pragma unroll
        for (int i = 0; i < 4; ++i) {
            af[i] = ld_frag(&Al[(wm * 64 + i * 16 + (lane & 15)) * 32 + kc8]);
            bf[i] = ld_frag(&Bl[(wn * 64 + i * 16 + (lane & 15)) * 32 + kc8]);
        }
        #pragma unroll
        for (int fi = 0; fi < 4; ++fi)
            #pragma unroll
            for (int fj = 0; fj < 4; ++fj)
                acc[fi][fj] = __builtin_amdgcn_mfma_f32_16x16x32_bf16(
                    af[fi], bf[fj], acc[fi][fj], 0, 0, 0);
        __syncthreads();
    }

    #pragma unroll
    for (int fi = 0; fi < 4; ++fi) {
        const int g0 = gtile + wm * 64 + fi * 16 + ((lane >> 4) << 2);
        const float4 v1 = *(const float4*)&bih[g0];
        const float4 v2 = *(const float4*)&bhh[g0];
        float badd[4] = {v1.x + v2.x, v1.y + v2.y, v1.z + v2.z, v1.w + v2.w};
        #pragma unroll
        for (int fj = 0; fj < 4; ++fj) {
            const int m = mtile + wn * 64 + fj * 16 + (lane & 15);
            const int b = m & 63, s = m >> 6;
            float* dst = &xg[s * XG_SSTRIDE + b];
            #pragma unroll
            for (int r = 0; r < 4; ++r)
                dst[(g0 + r) * 64] = acc[fi][fj][r] + badd[r];
        }
    }
}

// --------------------------------------------------------- K2: LSTM (persistent)
// 32 blocks = 4 batch-groups (bg) x 8 unit-slices (ug); block owns 16 batches
// x 64 units, weights register-resident. NO flags, NO producer drain: h is
// published as self-validating tagged u32 {step:16|h_bf16:16} (dword stores
// are atomic). Consumers poll the data itself at LLC; one syncthreads/step;
// LDS h-tile double-buffered. Step 0 skips the recurrent GEMM (h0 = 0).
#define LSTM_NBLK 32

__global__ __attribute__((amdgpu_flat_work_group_size(512, 512),
                          amdgpu_waves_per_eu(2, 2)))
void k2_lstm(
    const u16* __restrict__ Whh,     // [2048][512] bf16
    const float* __restrict__ xg,    // [S][G][B]
    u32* __restrict__ thbuf,         // [2][64][512] tagged u32 (zeroed)
    u16* __restrict__ hidden)        // [8192][512] bf16
{
    __shared__ __align__(16) u16 hl[2][16 * 528];   // dbuf [16 rows][512+16]

    const int t = threadIdx.x, lane = t & 63, w = t >> 6;   // 8 waves
    const int bg = blockIdx.x >> 3, ug = blockIdx.x & 7;
    const int j = lane & 15;
    const int kc8 = (lane >> 4) * 8;

    // wave w owns units ug*64 + w*8 .. +7, all 4 gates (2 MFMA N-tiles).
    const int ubase = ug * 64 + w * 8;
    const int grow0 = (j & 3) * 512 + ubase + (j >> 2);
    const int grow1 = grow0 + 4;

    bf16x8 bw0[16], bw1[16];
    #pragma unroll
    for (int kk = 0; kk < 16; ++kk) {
        bw0[kk] = ld_frag(&Whh[grow0 * NH + kk * 32 + kc8]);
        bw1[kk] = ld_frag(&Whh[grow1 * NH + kk * 32 + kc8]);
    }
    #pragma unroll
    for (int kk = 0; kk < 16; ++kk) {     // pin weights (one-time)
        f32x4 w0 = __builtin_bit_cast(f32x4, bw0[kk]);
        f32x4 w1 = __builtin_bit_cast(f32x4, bw1[kk]);
        asm volatile("" : "+v"(w0), "+v"(w1));
        bw0[kk] = __builtin_bit_cast(bf16x8, w0);
        bw1[kk] = __builtin_bit_cast(bf16x8, w1);
    }

    // staging: thread t owns 16 tagged u32 (64B): row t>>5, cols (t&31)*16..+15
    const int srow = t >> 5;
    const int scb  = (t & 31) * 16;
    const int soff = (bg * 16 + srow) * NH + scb;

    // post-transpose identities
    const int p  = lane & 3;
    const int q  = (lane >> 2) & 3;
    const int mb = (lane >> 4) * 4;
    const int bat = bg * 16 + mb + p;
    const int un0 = ubase + q;                   // owns un0 and un0+4
    const bool sl = ((lane & 4) == 0);           // even-q lanes store hidden pairs

    const int xoff0 = grow0 * 64 + bg * 16 + mb;
    const int xoff1 = grow1 * 64 + bg * 16 + mb;

    float4 xv0 = *(const float4*)&xg[xoff0];
    float4 xv1 = *(const float4*)&xg[xoff1];
    float cA = 0.f, cB = 0.f;

    for (int step = 0; step < NS; ++step) {
        // prefetch next step's xg (plain cached loads, in flight across poll)
        float4 xn0 = {0, 0, 0, 0}, xn1 = {0, 0, 0, 0};
        if (step + 1 < NS) {
            const float* xb = &xg[(step + 1) * XG_SSTRIDE];
            xn0 = *(const float4*)&xb[xoff0];
            xn1 = *(const float4*)&xb[xoff1];
        }

        f32x4 a00 = {0, 0, 0, 0}, a01 = {0, 0, 0, 0};
        f32x4 a10 = {0, 0, 0, 0}, a11 = {0, 0, 0, 0};

        if (step > 0) {
            const int par = step & 1;
            // poll tagged h_step at LLC, strip tags into LDS
            const u32* src = thbuf + par * (NB * NH) + soff;
            u16* dst = &hl[par][srow * 528 + scb];
            u32x4 c0, c1, c2, c3;
            load_llc64(src, c0, c1, c2, c3);
            commit_chunk(c0, src,      dst,      (u32)step);
            commit_chunk(c1, src + 4,  dst + 4,  (u32)step);
            commit_chunk(c2, src + 8,  dst + 8,  (u32)step);
            commit_chunk(c3, src + 12, dst + 12, (u32)step);
            __syncthreads();

            #pragma unroll
            for (int kk = 0; kk < 16; ++kk) {
                bf16x8 av = *(const bf16x8*)&hl[par][j * 528 + kk * 32 + kc8];
                if (kk & 1) {
                    a01 = __builtin_amdgcn_mfma_f32_16x16x32_bf16(av, bw0[kk], a01, 0, 0, 0);
                    a11 = __builtin_amdgcn_mfma_f32_16x16x32_bf16(av, bw1[kk], a11, 0, 0, 0);
                } else {
                    a00 = __builtin_amdgcn_mfma_f32_16x16x32_bf16(av, bw0[kk], a00, 0, 0, 0);
                    a10 = __builtin_amdgcn_mfma_f32_16x16x32_bf16(av, bw1[kk], a10, 0, 0, 0);
                }
            }
        }

        float v0[4], v1[4];
        #pragma unroll
        for (int r = 0; r < 4; ++r) {
            v0[r] = a00[r] + a01[r] + (&xv0.x)[r];
            v1[r] = a10[r] + a11[r] + (&xv1.x)[r];
        }
        quad_transpose(v0, p);
        quad_transpose(v1, p);

        float h0 = lstm_cell(v0, cA);
        float h1 = lstm_cell(v1, cB);
        u32 hb0 = f2bf(h0), hb1 = f2bf(h1);

        // publish tagged h_{step+1}: fire-and-forget, no drain, no flag
        if (step + 1 < NS) {
            u32 tg = (u32)(step + 1) << 16;
            u32* hp = thbuf + ((step + 1) & 1) * (NB * NH) + bat * NH;
            store_llc(&hp[un0],     tg | hb0);
            store_llc(&hp[un0 + 4], tg | hb1);
        }
        // hidden history (plain stores, flushed at kernel end)
        u32 o0 = (u32)__shfl_xor((int)hb0, 4);
        u32 o1 = (u32)__shfl_xor((int)hb1, 4);
        if (sl) {
            *(u32*)&hidden[(bat * NS + step) * NH + un0]     = hb0 | (o0 << 16);
            *(u32*)&hidden[(bat * NS + step) * NH + un0 + 4] = hb1 | (o1 << 16);
        }
        xv0 = xn0; xv1 = xn1;
    }
}

// ------------------------------------- K3: logits = hidden @ W_cls^T + b_cls
__global__ __launch_bounds__(256) void k3_cls(
    const u16* __restrict__ Wc, const u16* __restrict__ hid,
    const float* __restrict__ bcls,
    float* __restrict__ out, float* __restrict__ lse)
{
    __shared__ u16x8 Al8[512];
    __shared__ u16x8 Bl8[512];
    __shared__ float red[2][128];
    u16* Al = (u16*)Al8;
    u16* Bl = (u16*)Bl8;

    const int t = threadIdx.x;
    const int lane = t & 63, w = t >> 6;
    const int wm = w >> 1, wn = w & 1;
    const int vtile = blockIdx.y * 128, mtile = blockIdx.x * 128;

    const int r0 = t >> 2, r1 = r0 + 64, q = t & 3;

    f32x4 acc[4][4];
    for (int i = 0; i < 4; ++i)
        for (int j2 = 0; j2 < 4; ++j2) acc[i][j2] = {0.f, 0.f, 0.f, 0.f};

    const int kc8 = (lane >> 4) * 8;
    for (int kk = 0; kk < 16; ++kk) {
        const int k0 = kk * 32;
        *(u16x8*)&Al[t * 8]         = *(const u16x8*)&Wc[(vtile + r0) * NH + k0 + q * 8];
        *(u16x8*)&Al[(t + 256) * 8] = *(const u16x8*)&Wc[(vtile + r1) * NH + k0 + q * 8];
        *(u16x8*)&Bl[t * 8]         = *(const u16x8*)&hid[(mtile + r0) * NH + k0 + q * 8];
        *(u16x8*)&Bl[(t + 256) * 8] = *(const u16x8*)&hid[(mtile + r1) * NH + k0 + q * 8];
        __syncthreads();
        bf16x8 af[4], bf[4];
        #pragma unroll
        for (int i = 0; i < 4; ++i) {
            af[i] = ld_frag(&Al[(wm * 64 + i * 16 + (lane & 15)) * 32 + kc8]);
            bf[i] = ld_frag(&Bl[(wn * 64 + i * 16 + (lane & 15)) * 32 + kc8]);
        }
        #pragma unroll
        for (int fi = 0; fi < 4; ++fi)
            #pragma unroll
            for (int fj = 0; fj < 4; ++fj)
                acc[fi][fj] = __builtin_amdgcn_mfma_f32_16x16x32_bf16(
                    af[fi], bf[fj], acc[fi][fj], 0, 0, 0);
        __syncthreads();
    }

    float lsum[4] = {0.f, 0.f, 0.f, 0.f};
    #pragma unroll
    for (int fi = 0; fi < 4; ++fi) {
        const int v0 = vtile + wm * 64 + fi * 16 + ((lane >> 4) << 2);
        const bool vok = (v0 < NV);
        float4 bc = {0.f, 0.f, 0.f, 0.f};
        if (vok) bc = *(const float4*)&bcls[v0];
        #pragma unroll
        for (int fj = 0; fj < 4; ++fj) {
            const int m = mtile + wn * 64 + fj * 16 + (lane & 15);
            const int b = m >> 7, s = m & 127;
            if (vok) {
                float* dst = &out[b * OUT_BSTRIDE + v0 * NS + s];
                float e = 0.f;
                #pragma unroll
                for (int r = 0; r < 4; ++r) {
                    float lg = acc[fi][fj][r] + (&bc.x)[r];
                    dst[r * NS] = lg;
                    e += __expf(lg);
                }
                lsum[fj] += e;
            }
        }
    }
    #pragma unroll
    for (int fj = 0; fj < 4; ++fj) {
        lsum[fj] += __shfl_xor(lsum[fj], 16);
        lsum[fj] += __shfl_xor(lsum[fj], 32);
    }
    if (lane < 16) {
        #pragma unroll
        for (int fj = 0; fj < 4; ++fj)
            red[wm][wn * 64 + fj * 16 + lane] = lsum[fj];
    }
    __syncthreads();
    if (t < 128) {
        const int m = mtile + t;
        atomicAdd(&lse[m], red[0][t] + red[1][t]);
    }
}

// ------------------------------------------------------------- K4/K5 epilogue
__global__ void k4_log(const float* __restrict__ lse, float* __restrict__ ll) {
    int i = blockIdx.x * 256 + threadIdx.x;
    if (i < NBS) ll[i] = logf(lse[i]);
}

__global__ void k5_norm(float* __restrict__ out, const float* __restrict__ ll) {
    const int total4 = NB * NV * NS / 4;   // 16,384,000
    float4* o4 = (float4*)out;
    for (int i = blockIdx.x * blockDim.x + threadIdx.x; i < total4;
         i += gridDim.x * blockDim.x) {
        const int i4 = i * 4;
        const int b = i4 / OUT_BSTRIDE;
        const int s = (i4 - b * OUT_BSTRIDE) & 127;
        float4 v = o4[i];
        const float4 l = *(const float4*)&ll[b * NS + s];
        v.x -= l.x; v.y -= l.y; v.z -= l.z; v.w -= l.w;
        o4[i] = v;
    }
}

// ---------------------------------------------------------------------------
extern "C" void kernel_launch(void* const* d_in, const int* in_sizes, int n_in,
                              void* d_out, int out_size, void* d_ws, size_t ws_size,
                              hipStream_t stream) {
    const int*   toks   = (const int*)d_in[0];
    const float* emb_f  = (const float*)d_in[1];
    const float* Wih_f  = (const float*)d_in[2];
    const float* Whh_f  = (const float*)d_in[3];
    const float* bih    = (const float*)d_in[4];
    const float* bhh    = (const float*)d_in[5];
    const float* Wcls_f = (const float*)d_in[6];
    const float* bcls   = (const float*)d_in[7];
    float* out = (float*)d_out;
    char*  ws  = (char*)d_ws;

    // workspace layout (bytes) — offsets kept from round 6
    float* lse    = (float*)(ws + 8192);       // 32768
    float* loglse = (float*)(ws + 40960);      // 32768
    u16*   embb   = (u16*)(ws + 204800);       // 4,096,000
    u16*   wihb   = (u16*)(ws + 4300800);      // 1,048,576
    u16*   whhb   = (u16*)(ws + 5349376);      // 2,097,152
    u16*   wclsb  = (u16*)(ws + 7446528);      // 8,388,608 (padded 8192 rows)
    u16*   hidden = (u16*)(ws + 15835136);     // 8,388,608

    // scratch regions inside d_out (262 MB):
    //   xg f32 [S][G][B] at offset 0 (67.1 MB)
    //   tagged h ping-pong at +80 MB (256 KB) — both overwritten by k3 later
    float* xg = out;
    u32* thbuf = (u32*)((char*)out + 80u * 1024u * 1024u);

    hipMemsetAsync(ws, 0, 73728, stream);              // lse + loglse
    hipMemsetAsync(thbuf, 0, 2 * NB * NH * 4, stream); // clear tags (per replay)
    hipMemsetAsync((char*)wclsb + NV * NH * 2, 0, (NVP - NV) * NH * 2, stream);

    cvt_bf16<<<1024, 256, 0, stream>>>(emb_f,  embb,  NV * NE / 8);
    cvt_bf16<<<256,  256, 0, stream>>>(Wih_f,  wihb,  NG * NE / 8);
    cvt_bf16<<<512,  256, 0, stream>>>(Whh_f,  whhb,  NG * NH / 8);
    cvt_bf16<<<1024, 256, 0, stream>>>(Wcls_f, wclsb, NV * NH / 8);

    k1_xgates<<<dim3(64, 16), 256, 0, stream>>>(wihb, embb, toks, bih, bhh, xg);
    k2_lstm<<<LSTM_NBLK, 512, 0, stream>>>(whhb, xg, thbuf, hidden);
    k3_cls<<<dim3(64, 64), 256, 0, stream>>>(wclsb, hidden, bcls, out, lse);
    k4_log<<<32, 256, 0, stream>>>(lse, loglse);
    k5_norm<<<2048, 256, 0, stream>>>(out, loglse);
}

// Round 8
// 684.305 us; speedup vs baseline: 1.2805x; 1.2805x over previous
//
#include <hip/hip_runtime.h>

// ---------------------------------------------------------------------------
// PoetryModel: embed -> x_gates GEMM -> LSTM(128 steps) -> classifier GEMM
//              -> log_softmax over V -> out (B, V, S) f32
// B=64 S=128 V=8000 E=256 H=512 G=4H=2048
// ---------------------------------------------------------------------------

using u16   = unsigned short;
using u32   = unsigned int;
using u16x8 = __attribute__((ext_vector_type(8))) u16;
using bf16x8 = __attribute__((ext_vector_type(8))) __bf16;
using f32x4 = __attribute__((ext_vector_type(4))) float;

#define NB   64        // batch
#define NS   128       // seq len
#define NV   8000      // vocab
#define NVP  8192      // vocab padded to tile
#define NE   256       // embed dim
#define NH   512       // hidden
#define NG   2048      // 4*H
#define NBS  8192      // B*S
#define OUT_BSTRIDE 1024000   // V*S
#define XG_SSTRIDE  131072    // G*B

__device__ inline u16 f2bf(float f) {
    unsigned x = __builtin_bit_cast(unsigned, f);
    unsigned r = (x + 0x7FFFu + ((x >> 16) & 1u)) >> 16;
    return (u16)r;
}

__device__ inline bf16x8 ld_frag(const u16* p) {
    u16x8 v = *(const u16x8*)p;
    return __builtin_bit_cast(bf16x8, v);
}

// LLC-coherent ops: bypass L1+L2, never create/consume dirty L2 lines.
__device__ inline u32 load_llc(const u32* p) {
    u32 v;
    asm volatile("global_load_dword %0, %1, off sc0 sc1\n\t"
                 "s_waitcnt vmcnt(0)"
                 : "=v"(v) : "v"(p) : "memory");
    return v;
}
__device__ inline f32x4 load_llc16(const void* p) {
    f32x4 v;
    asm volatile("global_load_dwordx4 %0, %1, off sc0 sc1\n\t"
                 "s_waitcnt vmcnt(0)"
                 : "=v"(v) : "v"(p) : "memory");
    return v;
}
__device__ inline void store_llc(u32* p, u32 v) {
    asm volatile("global_store_dword %0, %1, off sc0 sc1"
                 :: "v"(p), "v"(v) : "memory");
}
// plain cached load, NO waitcnt: caller guarantees a covering vmcnt before use
__device__ inline void prefetch16(f32x4& d, const float* p) {
    asm volatile("global_load_dwordx4 %0, %1, off"
                 : "=v"(d) : "v"(p) : "memory");
}

// 4x4 transpose across lane quad {p} x element {r} (verified round 3)
__device__ inline void quad_transpose(float v[4], int p) {
    float tb[4];
    #pragma unroll
    for (int q2 = 0; q2 < 4; ++q2) tb[q2] = __shfl_xor(v[q2 ^ 2], 2);
    #pragma unroll
    for (int q2 = 0; q2 < 4; ++q2) v[q2] = (((q2 ^ p) & 2) ? tb[q2] : v[q2]);
    #pragma unroll
    for (int q2 = 0; q2 < 4; ++q2) tb[q2] = __shfl_xor(v[q2 ^ 1], 1);
    #pragma unroll
    for (int q2 = 0; q2 < 4; ++q2) v[q2] = (((q2 ^ p) & 1) ? tb[q2] : v[q2]);
}

__device__ inline float lstm_cell(const float v[4], float& c) {
    float i_ = 1.f / (1.f + __expf(-v[0]));
    float f_ = 1.f / (1.f + __expf(-v[1]));
    float e2 = __expf(2.f * v[2]);
    float g_ = 1.f - 2.f / (e2 + 1.f);
    float o_ = 1.f / (1.f + __expf(-v[3]));
    c = f_ * c + i_ * g_;
    float e2c = __expf(2.f * c);
    return o_ * (1.f - 2.f / (e2c + 1.f));
}

// ---------------------------------------------------------------- converts
__global__ void cvt_bf16(const float* __restrict__ s, u16* __restrict__ d, int n8) {
    const float4* s4 = (const float4*)s;
    for (int i = blockIdx.x * blockDim.x + threadIdx.x; i < n8;
         i += gridDim.x * blockDim.x) {
        float4 a = s4[2 * i], b = s4[2 * i + 1];
        u16x8 o;
        o[0] = f2bf(a.x); o[1] = f2bf(a.y); o[2] = f2bf(a.z); o[3] = f2bf(a.w);
        o[4] = f2bf(b.x); o[5] = f2bf(b.y); o[6] = f2bf(b.z); o[7] = f2bf(b.w);
        ((u16x8*)d)[i] = o;
    }
}

// ------------------------------------------------- K1: x_gates = x @ W_ih^T
__global__ __launch_bounds__(256) void k1_xgates(
    const u16* __restrict__ Wih, const u16* __restrict__ emb,
    const int* __restrict__ toks,
    const float* __restrict__ bih, const float* __restrict__ bhh,
    float* __restrict__ xg)
{
    __shared__ u16x8 Al8[512];   // [128][32] bf16
    __shared__ u16x8 Bl8[512];
    u16* Al = (u16*)Al8;
    u16* Bl = (u16*)Bl8;

    const int t = threadIdx.x;
    const int lane = t & 63, w = t >> 6;
    const int wm = w >> 1, wn = w & 1;
    const int gtile = blockIdx.y * 128, mtile = blockIdx.x * 128;

    const int r0 = t >> 2, r1 = r0 + 64, q = t & 3;
    const int m0 = mtile + r0, m1 = mtile + r1;
    const int tok0 = toks[(m0 & 63) * NS + (m0 >> 6)];
    const int tok1 = toks[(m1 & 63) * NS + (m1 >> 6)];

    f32x4 acc[4][4];
    for (int i = 0; i < 4; ++i)
        for (int j = 0; j < 4; ++j) acc[i][j] = {0.f, 0.f, 0.f, 0.f};

    const int kc8 = (lane >> 4) * 8;
    for (int kk = 0; kk < 8; ++kk) {
        const int k0 = kk * 32;
        *(u16x8*)&Al[t * 8]         = *(const u16x8*)&Wih[(gtile + r0) * NE + k0 + q * 8];
        *(u16x8*)&Al[(t + 256) * 8] = *(const u16x8*)&Wih[(gtile + r1) * NE + k0 + q * 8];
        *(u16x8*)&Bl[t * 8]         = *(const u16x8*)&emb[tok0 * NE + k0 + q * 8];
        *(u16x8*)&Bl[(t + 256) * 8] = *(const u16x8*)&emb[tok1 * NE + k0 + q * 8];
        __syncthreads();
        bf16x8 af[4], bf[4];
        #pragma unroll
        for (int i = 0; i < 4; ++i) {
            af[i] = ld_frag(&Al[(wm * 64 + i * 16 + (lane & 15)) * 32 + kc8]);
            bf[i] = ld_frag(&Bl[(wn * 64 + i * 16 + (lane & 15)) * 32 + kc8]);
        }
        #pragma unroll
        for (int fi = 0; fi < 4; ++fi)
            #pragma unroll
            for (int fj = 0; fj < 4; ++fj)
                acc[fi][fj] = __builtin_amdgcn_mfma_f32_16x16x32_bf16(
                    af[fi], bf[fj], acc[fi][fj], 0, 0, 0);
        __syncthreads();
    }

    #pragma unroll
    for (int fi = 0; fi < 4; ++fi) {
        const int g0 = gtile + wm * 64 + fi * 16 + ((lane >> 4) << 2);
        const float4 v1 = *(const float4*)&bih[g0];
        const float4 v2 = *(const float4*)&bhh[g0];
        float badd[4] = {v1.x + v2.x, v1.y + v2.y, v1.z + v2.z, v1.w + v2.w};
        #pragma unroll
        for (int fj = 0; fj < 4; ++fj) {
            const int m = mtile + wn * 64 + fj * 16 + (lane & 15);
            const int b = m & 63, s = m >> 6;
            float* dst = &xg[s * XG_SSTRIDE + b];
            #pragma unroll
            for (int r = 0; r < 4; ++r)
                dst[(g0 + r) * 64] = acc[fi][fj][r] + badd[r];
        }
    }
}

// --------------------------------------------------------- K2: LSTM (persistent)
// R4 structure (best: 394us): 64 blocks = 8 batch-groups x 8 unit-slices,
// 8 batches x 64 units per block, weights register-resident, h staged via LDS,
// 8-flag group rendezvous at LLC (sc0 sc1). New this round:
//  - counted-drain barrier: publish stores, then xg prefetch (asm loads,
//    newest), then s_waitcnt vmcnt(2) + s_barrier -> flag no longer waits on
//    the HBM prefetch latency; in-order vmcnt retirement guarantees stores
//    are drained.
//  - x2 unrolled step loop: prefetch step+2 lands in the register set that
//    step+2 reads (no copies; covered by the intervening step's vmcnt).
//  - pad lanes (kg>=2) fully guarded: no OOB stores, half the xg reads.
#define LSTM_NBLK 64

__global__ __launch_bounds__(512, 2) void k2_lstm(
    const u16* __restrict__ Whh,     // [2048][512] bf16
    const float* __restrict__ xg,    // [S][G][B]
    u16* __restrict__ hbuf,          // [2][64][512] bf16 ping-pong
    u16* __restrict__ hidden,        // [8192][512] bf16
    u32* __restrict__ flags)         // [64] on 128B-strided lines (zeroed)
{
    __shared__ __align__(16) u16 hl[16 * 528];   // [16 rows][512+16 pad] bf16

    const int t = threadIdx.x, lane = t & 63, w = t >> 6;   // 8 waves
    const int bg = blockIdx.x >> 3, ug = blockIdx.x & 7;
    const int j = lane & 15, kg = lane >> 4;
    const int kc8 = kg * 8;

    // wave w owns units ug*64 + w*8 .. +7, all 4 gates (2 MFMA N-tiles).
    const int ubase = ug * 64 + w * 8;
    const int grow0 = (j & 3) * 512 + ubase + (j >> 2);
    const int grow1 = grow0 + 4;

    bf16x8 bw0[16], bw1[16];
    #pragma unroll
    for (int kk = 0; kk < 16; ++kk) {
        bw0[kk] = ld_frag(&Whh[grow0 * NH + kk * 32 + kc8]);
        bw1[kk] = ld_frag(&Whh[grow1 * NH + kk * 32 + kc8]);
    }
    #pragma unroll
    for (int kk = 0; kk < 16; ++kk) {     // pin weights (one-time)
        f32x4 w0 = __builtin_bit_cast(f32x4, bw0[kk]);
        f32x4 w1 = __builtin_bit_cast(f32x4, bw1[kk]);
        asm volatile("" : "+v"(w0), "+v"(w1));
        bw0[kk] = __builtin_bit_cast(bf16x8, w0);
        bw1[kk] = __builtin_bit_cast(bf16x8, w1);
    }

    // zero LDS pad rows 8..15 once (MFMA A rows 8..15 read zeros)
    {
        u16x8 z = {0, 0, 0, 0, 0, 0, 0, 0};
        *(u16x8*)&hl[(8 + (t >> 6)) * 528 + (t & 63) * 8] = z;
    }

    // staging: thread t loads 16B of h: batch row t>>6 (0..7), col (t&63)*8
    const int srow = t >> 6, scol = (t & 63) * 8;
    const int soff = (bg * 8 + srow) * NH + scol;
    u16* hl_w = &hl[srow * 528 + scol];

    // post-transpose identities
    const int p  = lane & 3;
    const int q  = (lane >> 2) & 3;
    const int mb = kg * 4;
    const bool real = (kg < 2);                  // batches 0..7 real, 8..15 pad
    const int bat = bg * 8 + mb + p;             // valid only when real
    const int un0 = ubase + q;
    const bool sl = real && ((lane & 4) == 0);   // store u32 pairs

    const int xo0 = grow0 * 64 + bg * 8 + mb;
    const int xo1 = grow1 * 64 + bg * 8 + mb;

    // even/odd register sets for xg (2-deep pipeline, no copies)
    f32x4 xvA0 = {0,0,0,0}, xvA1 = {0,0,0,0};
    f32x4 xvB0 = {0,0,0,0}, xvB1 = {0,0,0,0};
    if (real) {
        xvA0 = *(const f32x4*)&xg[xo0];
        xvA1 = *(const f32x4*)&xg[xo1];
        xvB0 = *(const f32x4*)&xg[XG_SSTRIDE + xo0];
        xvB1 = *(const f32x4*)&xg[XG_SSTRIDE + xo1];
    }
    float cA = 0.f, cB = 0.f;

    auto body = [&](int step, f32x4& X0, f32x4& X1) {
        f32x4 a00 = {0,0,0,0}, a01 = {0,0,0,0};
        f32x4 a10 = {0,0,0,0}, a11 = {0,0,0,0};

        if (step > 0) {
            // poll the group's 8 flags (lanes 0..7 of every wave)
            if (lane < 8) {
                const u32* fp = &flags[(bg * 8 + lane) * 32];
                while ((int)load_llc(fp) < step) __builtin_amdgcn_s_sleep(1);
            }
            // stage h_step (8KB) from LLC into LDS; internal vmcnt(0) also
            // retires the step-2 prefetch before any use of X0/X1
            f32x4 hv = load_llc16(&hbuf[(step & 1) * (NB * NH) + soff]);
            *(f32x4*)hl_w = hv;
            __syncthreads();

            #pragma unroll
            for (int kk = 0; kk < 16; ++kk) {
                bf16x8 av = *(const bf16x8*)&hl[j * 528 + kk * 32 + kc8];
                if (kk & 1) {
                    a01 = __builtin_amdgcn_mfma_f32_16x16x32_bf16(av, bw0[kk], a01, 0, 0, 0);
                    a11 = __builtin_amdgcn_mfma_f32_16x16x32_bf16(av, bw1[kk], a11, 0, 0, 0);
                } else {
                    a00 = __builtin_amdgcn_mfma_f32_16x16x32_bf16(av, bw0[kk], a00, 0, 0, 0);
                    a10 = __builtin_amdgcn_mfma_f32_16x16x32_bf16(av, bw1[kk], a10, 0, 0, 0);
                }
            }
        }

        float v0[4], v1[4];
        #pragma unroll
        for (int r = 0; r < 4; ++r) {
            v0[r] = a00[r] + a01[r] + X0[r];
            v1[r] = a10[r] + a11[r] + X1[r];
        }
        quad_transpose(v0, p);
        quad_transpose(v1, p);

        float h0 = lstm_cell(v0, cA);
        float h1 = lstm_cell(v1, cB);
        u32 hb0 = f2bf(h0), hb1 = f2bf(h1);
        u32 o0 = (u32)__shfl_xor((int)hb0, 4);   // partner holds unit un0^1
        u32 o1 = (u32)__shfl_xor((int)hb1, 4);
        u32 pr0 = hb0 | (o0 << 16);
        u32 pr1 = hb1 | (o1 << 16);

        // 1) publish h_{step+1} (oldest vmem ops at the barrier)
        if (step + 1 < NS && sl) {
            u32* hp = (u32*)&hbuf[((step + 1) & 1) * (NB * NH) + bat * NH + un0];
            store_llc(hp, pr0);
            store_llc(hp + 2, pr1);              // unit un0+4
        }
        // 2) prefetch xg[step+2] into this parity's registers (newest ops)
        if (step + 2 < NS && real) {
            const float* xb = &xg[(step + 2) * XG_SSTRIDE];
            prefetch16(X0, &xb[xo0]);
            prefetch16(X1, &xb[xo1]);
        }
        // 3) counted drain: stores retired, prefetch stays in flight
        if (step + 2 < NS)
            asm volatile("s_waitcnt vmcnt(2) lgkmcnt(0)\n\ts_barrier" ::: "memory");
        else
            asm volatile("s_waitcnt vmcnt(0) lgkmcnt(0)\n\ts_barrier" ::: "memory");
        // 4) flag up — consumers unblock without waiting on our HBM reads
        if (step + 1 < NS && t == 0)
            store_llc(&flags[blockIdx.x * 32], (u32)(step + 1));
        // 5) hidden history (plain stores; drained by next step's vmcnt(0))
        if (sl) {
            *(u32*)&hidden[(bat * NS + step) * NH + un0] = pr0;
            *(u32*)&hidden[(bat * NS + step) * NH + un0 + 4] = pr1;
        }
    };

    for (int s2 = 0; s2 < NS / 2; ++s2) {
        body(2 * s2,     xvA0, xvA1);
        body(2 * s2 + 1, xvB0, xvB1);
    }
}

// ------------------------------------- K3: logits = hidden @ W_cls^T + b_cls
__global__ __launch_bounds__(256) void k3_cls(
    const u16* __restrict__ Wc, const u16* __restrict__ hid,
    const float* __restrict__ bcls,
    float* __restrict__ out, float* __restrict__ lse)
{
    __shared__ u16x8 Al8[512];
    __shared__ u16x8 Bl8[512];
    __shared__ float red[2][128];
    u16* Al = (u16*)Al8;
    u16* Bl = (u16*)Bl8;

    const int t = threadIdx.x;
    const int lane = t & 63, w = t >> 6;
    const int wm = w >> 1, wn = w & 1;
    const int vtile = blockIdx.y * 128, mtile = blockIdx.x * 128;

    const int r0 = t >> 2, r1 = r0 + 64, q = t & 3;

    f32x4 acc[4][4];
    for (int i = 0; i < 4; ++i)
        for (int j2 = 0; j2 < 4; ++j2) acc[i][j2] = {0.f, 0.f, 0.f, 0.f};

    const int kc8 = (lane >> 4) * 8;
    for (int kk = 0; kk < 16; ++kk) {
        const int k0 = kk * 32;
        *(u16x8*)&Al[t * 8]         = *(const u16x8*)&Wc[(vtile + r0) * NH + k0 + q * 8];
        *(u16x8*)&Al[(t + 256) * 8] = *(const u16x8*)&Wc[(vtile + r1) * NH + k0 + q * 8];
        *(u16x8*)&Bl[t * 8]         = *(const u16x8*)&hid[(mtile + r0) * NH + k0 + q * 8];
        *(u16x8*)&Bl[(t + 256) * 8] = *(const u16x8*)&hid[(mtile + r1) * NH + k0 + q * 8];
        __syncthreads();
        bf16x8 af[4], bf[4];
        #pragma unroll
        for (int i = 0; i < 4; ++i) {
            af[i] = ld_frag(&Al[(wm * 64 + i * 16 + (lane & 15)) * 32 + kc8]);
            bf[i] = ld_frag(&Bl[(wn * 64 + i * 16 + (lane & 15)) * 32 + kc8]);
        }
        #pragma unroll
        for (int fi = 0; fi < 4; ++fi)
            #pragma unroll
            for (int fj = 0; fj < 4; ++fj)
                acc[fi][fj] = __builtin_amdgcn_mfma_f32_16x16x32_bf16(
                    af[fi], bf[fj], acc[fi][fj], 0, 0, 0);
        __syncthreads();
    }

    float lsum[4] = {0.f, 0.f, 0.f, 0.f};
    #pragma unroll
    for (int fi = 0; fi < 4; ++fi) {
        const int v0 = vtile + wm * 64 + fi * 16 + ((lane >> 4) << 2);
        const bool vok = (v0 < NV);
        float4 bc = {0.f, 0.f, 0.f, 0.f};
        if (vok) bc = *(const float4*)&bcls[v0];
        #pragma unroll
        for (int fj = 0; fj < 4; ++fj) {
            const int m = mtile + wn * 64 + fj * 16 + (lane & 15);
            const int b = m >> 7, s = m & 127;
            if (vok) {
                float* dst = &out[b * OUT_BSTRIDE + v0 * NS + s];
                float e = 0.f;
                #pragma unroll
                for (int r = 0; r < 4; ++r) {
                    float lg = acc[fi][fj][r] + (&bc.x)[r];
                    dst[r * NS] = lg;
                    e += __expf(lg);
                }
                lsum[fj] += e;
            }
        }
    }
    #pragma unroll
    for (int fj = 0; fj < 4; ++fj) {
        lsum[fj] += __shfl_xor(lsum[fj], 16);
        lsum[fj] += __shfl_xor(lsum[fj], 32);
    }
    if (lane < 16) {
        #pragma unroll
        for (int fj = 0; fj < 4; ++fj)
            red[wm][wn * 64 + fj * 16 + lane] = lsum[fj];
    }
    __syncthreads();
    if (t < 128) {
        const int m = mtile + t;
        atomicAdd(&lse[m], red[0][t] + red[1][t]);
    }
}

// ------------------------------------------------------------- K4/K5 epilogue
__global__ void k4_log(const float* __restrict__ lse, float* __restrict__ ll) {
    int i = blockIdx.x * 256 + threadIdx.x;
    if (i < NBS) ll[i] = logf(lse[i]);
}

__global__ void k5_norm(float* __restrict__ out, const float* __restrict__ ll) {
    const int total4 = NB * NV * NS / 4;   // 16,384,000
    float4* o4 = (float4*)out;
    for (int i = blockIdx.x * blockDim.x + threadIdx.x; i < total4;
         i += gridDim.x * blockDim.x) {
        const int i4 = i * 4;
        const int b = i4 / OUT_BSTRIDE;
        const int s = (i4 - b * OUT_BSTRIDE) & 127;
        float4 v = o4[i];
        const float4 l = *(const float4*)&ll[b * NS + s];
        v.x -= l.x; v.y -= l.y; v.z -= l.z; v.w -= l.w;
        o4[i] = v;
    }
}

// ---------------------------------------------------------------------------
extern "C" void kernel_launch(void* const* d_in, const int* in_sizes, int n_in,
                              void* d_out, int out_size, void* d_ws, size_t ws_size,
                              hipStream_t stream) {
    const int*   toks   = (const int*)d_in[0];
    const float* emb_f  = (const float*)d_in[1];
    const float* Wih_f  = (const float*)d_in[2];
    const float* Whh_f  = (const float*)d_in[3];
    const float* bih    = (const float*)d_in[4];
    const float* bhh    = (const float*)d_in[5];
    const float* Wcls_f = (const float*)d_in[6];
    const float* bcls   = (const float*)d_in[7];
    float* out = (float*)d_out;
    char*  ws  = (char*)d_ws;

    // workspace layout (bytes)
    u32*   flags  = (u32*)(ws + 0);            // 8192 (64 x 128B lines)
    float* lse    = (float*)(ws + 8192);       // 32768
    float* loglse = (float*)(ws + 40960);      // 32768
    u16*   hbuf   = (u16*)(ws + 73728);        // 131072 (no memset needed)
    u16*   embb   = (u16*)(ws + 204800);       // 4,096,000
    u16*   wihb   = (u16*)(ws + 4300800);      // 1,048,576
    u16*   whhb   = (u16*)(ws + 5349376);      // 2,097,152
    u16*   wclsb  = (u16*)(ws + 7446528);      // 8,388,608 (padded 8192 rows)
    u16*   hidden = (u16*)(ws + 15835136);     // 8,388,608

    // x_gates f32 [S][G][B] lives in d_out scratch (16.8M floats < 65.5M)
    float* xg = out;

    hipMemsetAsync(ws, 0, 73728, stream);      // flags + lse + loglse
    hipMemsetAsync((char*)wclsb + NV * NH * 2, 0, (NVP - NV) * NH * 2, stream);

    cvt_bf16<<<1024, 256, 0, stream>>>(emb_f,  embb,  NV * NE / 8);
    cvt_bf16<<<256,  256, 0, stream>>>(Wih_f,  wihb,  NG * NE / 8);
    cvt_bf16<<<512,  256, 0, stream>>>(Whh_f,  whhb,  NG * NH / 8);
    cvt_bf16<<<1024, 256, 0, stream>>>(Wcls_f, wclsb, NV * NH / 8);

    k1_xgates<<<dim3(64, 16), 256, 0, stream>>>(wihb, embb, toks, bih, bhh, xg);
    k2_lstm<<<LSTM_NBLK, 512, 0, stream>>>(whhb, xg, hbuf, hidden, flags);
    k3_cls<<<dim3(64, 64), 256, 0, stream>>>(wclsb, hidden, bcls, out, lse);
    k4_log<<<32, 256, 0, stream>>>(lse, loglse);
    k5_norm<<<2048, 256, 0, stream>>>(out, loglse);
}